// Round 2
// baseline (421.677 us; speedup 1.0000x reference)
//
#include <hip/hip_runtime.h>

// SSIM loss v4 — row-pair packed-FP32 formulation:
//   - 1 column per thread, input rows streamed in PAIRS -> every hot op is a
//     v_pk_*_f32 on a {rowA,rowB} v2f with naturally register-aligned operands
//   - LDS entry = float4 {img1[rA], img1[rB], img2[rA], img2[rB]} per column:
//     horizontal 11-tap conv = 11 aligned ds_read_b128, halves are v2f operands
//   - vertical conv: 6-entry row-pair ring (60 VGPRs), per ring entry a pk-dot
//     with constant weight pairs {g[2m],g[2m+1]} / {g[2m-1],g[2m]}, lane-sum at
//     the end. Zero shuffle movs.
//   - triple-buffered LDS, one barrier per row-PAIR (37/block), global prefetch
//   - v4: __launch_bounds__(256,6) — v3's (256,3) capped residency at 3
//     blocks/CU (OccupancyPercent 33.6, VALUBusy 65%). 6 blocks/CU makes the
//     whole 1536-block grid co-resident (6/CU exactly); VGPR=64 <= 84 and
//     LDS 6x13.3KB = 80KB <= 160KB both fit.
//   (resubmit: round-1 bench was an MI355X container-acquisition failure, not
//    a kernel failure — no counters were produced, so the experiment re-runs.)
// B=32, C=3, H=W=512 fp32; zero padding (pad=5) matches lax conv semantics.

typedef float v2f __attribute__((ext_vector_type(2)));
typedef float v4f __attribute__((ext_vector_type(4)));

constexpr int IMG    = 512;
constexpr int TPB    = 256;          // threads/block; 1 col/thread
constexpr int SH     = 64;           // output rows per block
constexpr int NPAIR  = 37;           // input row-pairs streamed (74 rows)
constexpr int LW     = 272;          // LDS float4 entries per buffer (8 pad each side)
constexpr int PLANES = 32 * 3;      // 96
constexpr double N_PIX = 25165824.0; // 32*3*512*512

__global__ __launch_bounds__(TPB, 6) void ssim_map_kernel(
    const float* __restrict__ img1, const float* __restrict__ img2,
    double* __restrict__ partial)
{
    constexpr float GW[11] = {
        0.0010283801f, 0.0075987583f, 0.0360007721f, 0.1093607008f,
        0.2130055439f, 0.2660117257f, 0.2130055439f, 0.1093607008f,
        0.0360007721f, 0.0075987583f, 0.0010283801f };
    // GWp[k+1] = GW[k], zero-extended both sides (for edge taps of row pairs)
    constexpr float GWp[13] = {
        0.0f,
        0.0010283801f, 0.0075987583f, 0.0360007721f, 0.1093607008f,
        0.2130055439f, 0.2660117257f, 0.2130055439f, 0.1093607008f,
        0.0360007721f, 0.0075987583f, 0.0010283801f,
        0.0f };

    __shared__ v4f  sbuf[3][LW];
    __shared__ float wsum[TPB / 64];

    const int tid   = threadIdx.x;
    const int x0    = blockIdx.x * TPB;     // 0 or 256
    const int y0    = blockIdx.y * SH;
    const int plane = blockIdx.z;

    const float* p1 = img1 + (size_t)plane * IMG * IMG;
    const float* p2 = img2 + (size_t)plane * IMG * IMG;

    // staging columns: main entry L=tid -> col x0+tid-8 ; halo entry L=256+tid
    // (tid<16) -> col x0+248+tid. Out-of-range columns/rows stage 0.0f.
    const int  c   = x0 + tid - 8;
    const bool cok = (unsigned)c < (unsigned)IMG;
    const int  c2  = x0 + 248 + tid;
    const bool c2ok = (unsigned)c2 < (unsigned)IMG;   // only used when tid<16

    // 6-entry row-pair rings for the 5 horizontally-convolved quantities
    v2f rg1[6], rg2[6], rg11[6], rg22[6], rg12[6];

    v2f accv = {0.0f, 0.0f};

    // prefetch registers for the next row pair (4 main + 4 halo)
    float pa1, pb1, pa2, pb2, qa1, qb1, qa2, qb2;
    auto prefetch = [&](int i) {
        const int  rA  = y0 - 5 + 2 * i;
        const int  rB  = rA + 1;
        const bool aok = (unsigned)rA < (unsigned)IMG;
        const bool bok = (unsigned)rB < (unsigned)IMG;
        const size_t oA = (size_t)rA * IMG;
        const size_t oB = (size_t)rB * IMG;
        pa1 = (aok && cok) ? p1[oA + c] : 0.0f;
        pb1 = (bok && cok) ? p1[oB + c] : 0.0f;
        pa2 = (aok && cok) ? p2[oA + c] : 0.0f;
        pb2 = (bok && cok) ? p2[oB + c] : 0.0f;
        if (tid < 16) {
            qa1 = (aok && c2ok) ? p1[oA + c2] : 0.0f;
            qb1 = (bok && c2ok) ? p1[oB + c2] : 0.0f;
            qa2 = (aok && c2ok) ? p2[oA + c2] : 0.0f;
            qb2 = (bok && c2ok) ? p2[oB + c2] : 0.0f;
        }
    };

    prefetch(0);

    for (int ib = 0; ib < NPAIR; ib += 6) {
#pragma unroll
        for (int j = 0; j < 6; ++j) {
            const int i = ib + j;
            if (i < NPAIR) {
                // stage prefetched row pair into LDS slot j%3 (ib%3==0 always)
                sbuf[j % 3][tid] = v4f{pa1, pb1, pa2, pb2};
                if (tid < 16) sbuf[j % 3][256 + tid] = v4f{qa1, qb1, qa2, qb2};

                if (i + 1 < NPAIR) prefetch(i + 1);

                __syncthreads();   // RAW on slot j%3; triple buffer kills WAR

                // horizontal 11-tap conv for this thread's column, both rows
                v2f a1 = {0,0}, a2 = {0,0}, a11 = {0,0}, a22 = {0,0}, a12 = {0,0};
                const v4f* sp = &sbuf[j % 3][tid + 3];
#pragma unroll
                for (int k = 0; k < 11; ++k) {
                    const v4f s  = sp[k];
                    const v2f x1 = __builtin_shufflevector(s, s, 0, 1);
                    const v2f x2 = __builtin_shufflevector(s, s, 2, 3);
                    const float g = GW[k];
                    const v2f t1 = g * x1;
                    const v2f t2 = g * x2;
                    a1 += t1;
                    a2 += t2;
                    a11 = __builtin_elementwise_fma(t1, x1, a11);
                    a22 = __builtin_elementwise_fma(t2, x2, a22);
                    a12 = __builtin_elementwise_fma(t1, x2, a12);
                }
                rg1[j] = a1;  rg2[j] = a2;
                rg11[j] = a11; rg22[j] = a22; rg12[j] = a12;
            }

            if (i >= 5 && i < NPAIR) {
                // vertical conv for output rows (y0+2q, y0+2q+1), q = i-5.
                // ring entry m (input pair q+m) sits at slot (j+1+m)%6.
                // out.x taps: {g[2m], g[2m+1]} ; out.y taps: {g[2m-1], g[2m]}
                v2f sx1={0,0}, sy1={0,0}, sx2={0,0}, sy2={0,0};
                v2f sx11={0,0}, sy11={0,0}, sx22={0,0}, sy22={0,0};
                v2f sx12={0,0}, sy12={0,0};
#pragma unroll
                for (int m = 0; m < 6; ++m) {
                    const int s = (j + 1 + m) % 6;
                    const v2f wx = { GWp[2*m + 1], GWp[2*m + 2] };
                    const v2f wy = { GWp[2*m],     GWp[2*m + 1] };
                    sx1  = __builtin_elementwise_fma(wx, rg1[s],  sx1);
                    sy1  = __builtin_elementwise_fma(wy, rg1[s],  sy1);
                    sx2  = __builtin_elementwise_fma(wx, rg2[s],  sx2);
                    sy2  = __builtin_elementwise_fma(wy, rg2[s],  sy2);
                    sx11 = __builtin_elementwise_fma(wx, rg11[s], sx11);
                    sy11 = __builtin_elementwise_fma(wy, rg11[s], sy11);
                    sx22 = __builtin_elementwise_fma(wx, rg22[s], sx22);
                    sy22 = __builtin_elementwise_fma(wy, rg22[s], sy22);
                    sx12 = __builtin_elementwise_fma(wx, rg12[s], sx12);
                    sy12 = __builtin_elementwise_fma(wy, rg12[s], sy12);
                }
                // lane-sum each pk-dot -> {row r, row r+1} packed values
                const v2f m1  = { sx1.x + sx1.y,  sy1.x + sy1.y };
                const v2f m2  = { sx2.x + sx2.y,  sy2.x + sy2.y };
                const v2f e11 = { sx11.x + sx11.y, sy11.x + sy11.y };
                const v2f e22 = { sx22.x + sx22.y, sy22.x + sy22.y };
                const v2f e12 = { sx12.x + sx12.y, sy12.x + sy12.y };

                const v2f mu11 = m1 * m1;
                const v2f mu22 = m2 * m2;
                const v2f mu12 = m1 * m2;
                const v2f zero = {0.0f, 0.0f};
                const v2f one  = {1.0f, 1.0f};
                const v2f sg1  = __builtin_elementwise_max(e11 - mu11, zero);
                const v2f sg2  = __builtin_elementwise_max(e22 - mu22, zero);
                const v2f sg12 = e12 - mu12;
                const v2f num = (2.0f * mu12 + 1e-4f) * (2.0f * sg12 + 9e-4f);
                const v2f den = (mu11 + mu22 + 1e-4f) * (sg1 + sg2 + 9e-4f);
                v2f v = { num.x * __builtin_amdgcn_rcpf(den.x),
                          num.y * __builtin_amdgcn_rcpf(den.y) };
                v = __builtin_elementwise_min(__builtin_elementwise_max(v, zero), one);
                accv += v;
            }
        }
    }

    float acc = accv.x + accv.y;
#pragma unroll
    for (int off = 32; off > 0; off >>= 1)
        acc += __shfl_down(acc, off, 64);
    if ((tid & 63) == 0) wsum[tid >> 6] = acc;
    __syncthreads();
    if (tid == 0) {
        double blocksum = 0.0;
#pragma unroll
        for (int w = 0; w < TPB / 64; ++w) blocksum += (double)wsum[w];
        atomicAdd(partial, blocksum);
    }
}

__global__ void ssim_finalize_kernel(const double* __restrict__ partial,
                                     float* __restrict__ out)
{
    out[0] = 1.0f - (float)(partial[0] / N_PIX);
}

extern "C" void kernel_launch(void* const* d_in, const int* in_sizes, int n_in,
                              void* d_out, int out_size, void* d_ws, size_t ws_size,
                              hipStream_t stream) {
    const float* img1 = (const float*)d_in[0];
    const float* img2 = (const float*)d_in[1];
    float* out = (float*)d_out;
    double* acc = (double*)d_ws;

    hipMemsetAsync(acc, 0, sizeof(double), stream);  // ws re-poisoned each launch

    dim3 grid(IMG / TPB, IMG / SH, PLANES);          // 2 x 8 x 96 = 1536 blocks
    ssim_map_kernel<<<grid, TPB, 0, stream>>>(img1, img2, acc);
    ssim_finalize_kernel<<<1, 1, 0, stream>>>(acc, out);
}

// Round 4
// 256.798 us; speedup vs baseline: 1.6421x; 1.6421x over previous
//
#include <hip/hip_runtime.h>

// SSIM loss v5 — row-pair packed-FP32 formulation:
//   - 1 column per thread, input rows streamed in PAIRS -> every hot op is a
//     v_pk_*_f32 on a {rowA,rowB} v2f with naturally register-aligned operands
//   - LDS entry = float4 {img1[rA], img1[rB], img2[rA], img2[rB]} per column:
//     horizontal 11-tap conv = 11 aligned ds_read_b128, halves are v2f operands
//   - vertical conv: 6-entry row-pair ring (60 VGPRs), per ring entry a pk-dot
//     with constant weight pairs {g[2m],g[2m+1]} / {g[2m-1],g[2m]}, lane-sum at
//     the end. Zero shuffle movs.
//   - triple-buffered LDS, one barrier per row-PAIR (37/block), global prefetch
//   - v5: __launch_bounds__(256) ONLY. History: (256,3) clamped residency to
//     ~3 blocks/CU (Occupancy 33.6%, VALUBusy 65%, 116us); (256,6) forced the
//     allocator under the ring working set -> spilled rings to scratch
//     (VGPR 64->40, WRITE_SIZE 48KB->200MB, VALUBusy 23%, 285us). The natural
//     need is ~64 VGPR -> 8 waves/SIMD allowed by HW; grid (6 blocks/CU) is
//     then the limiter. No waves-per-eu annotation = no clamp, no spill.
//     Spill tripwire for future edits: WRITE_SIZE must stay ~KB-scale.
//   (resubmit: round-3 bench was an MI355X container-acquisition failure, not
//    a kernel failure — no counters were produced, so the experiment re-runs.)
// B=32, C=3, H=W=512 fp32; zero padding (pad=5) matches lax conv semantics.

typedef float v2f __attribute__((ext_vector_type(2)));
typedef float v4f __attribute__((ext_vector_type(4)));

constexpr int IMG    = 512;
constexpr int TPB    = 256;          // threads/block; 1 col/thread
constexpr int SH     = 64;           // output rows per block
constexpr int NPAIR  = 37;           // input row-pairs streamed (74 rows)
constexpr int LW     = 272;          // LDS float4 entries per buffer (8 pad each side)
constexpr int PLANES = 32 * 3;      // 96
constexpr double N_PIX = 25165824.0; // 32*3*512*512

__global__ __launch_bounds__(TPB) void ssim_map_kernel(
    const float* __restrict__ img1, const float* __restrict__ img2,
    double* __restrict__ partial)
{
    constexpr float GW[11] = {
        0.0010283801f, 0.0075987583f, 0.0360007721f, 0.1093607008f,
        0.2130055439f, 0.2660117257f, 0.2130055439f, 0.1093607008f,
        0.0360007721f, 0.0075987583f, 0.0010283801f };
    // GWp[k+1] = GW[k], zero-extended both sides (for edge taps of row pairs)
    constexpr float GWp[13] = {
        0.0f,
        0.0010283801f, 0.0075987583f, 0.0360007721f, 0.1093607008f,
        0.2130055439f, 0.2660117257f, 0.2130055439f, 0.1093607008f,
        0.0360007721f, 0.0075987583f, 0.0010283801f,
        0.0f };

    __shared__ v4f  sbuf[3][LW];
    __shared__ float wsum[TPB / 64];

    const int tid   = threadIdx.x;
    const int x0    = blockIdx.x * TPB;     // 0 or 256
    const int y0    = blockIdx.y * SH;
    const int plane = blockIdx.z;

    const float* p1 = img1 + (size_t)plane * IMG * IMG;
    const float* p2 = img2 + (size_t)plane * IMG * IMG;

    // staging columns: main entry L=tid -> col x0+tid-8 ; halo entry L=256+tid
    // (tid<16) -> col x0+248+tid. Out-of-range columns/rows stage 0.0f.
    const int  c   = x0 + tid - 8;
    const bool cok = (unsigned)c < (unsigned)IMG;
    const int  c2  = x0 + 248 + tid;
    const bool c2ok = (unsigned)c2 < (unsigned)IMG;   // only used when tid<16

    // 6-entry row-pair rings for the 5 horizontally-convolved quantities
    v2f rg1[6], rg2[6], rg11[6], rg22[6], rg12[6];

    v2f accv = {0.0f, 0.0f};

    // prefetch registers for the next row pair (4 main + 4 halo)
    float pa1, pb1, pa2, pb2, qa1, qb1, qa2, qb2;
    auto prefetch = [&](int i) {
        const int  rA  = y0 - 5 + 2 * i;
        const int  rB  = rA + 1;
        const bool aok = (unsigned)rA < (unsigned)IMG;
        const bool bok = (unsigned)rB < (unsigned)IMG;
        const size_t oA = (size_t)rA * IMG;
        const size_t oB = (size_t)rB * IMG;
        pa1 = (aok && cok) ? p1[oA + c] : 0.0f;
        pb1 = (bok && cok) ? p1[oB + c] : 0.0f;
        pa2 = (aok && cok) ? p2[oA + c] : 0.0f;
        pb2 = (bok && cok) ? p2[oB + c] : 0.0f;
        if (tid < 16) {
            qa1 = (aok && c2ok) ? p1[oA + c2] : 0.0f;
            qb1 = (bok && c2ok) ? p1[oB + c2] : 0.0f;
            qa2 = (aok && c2ok) ? p2[oA + c2] : 0.0f;
            qb2 = (bok && c2ok) ? p2[oB + c2] : 0.0f;
        }
    };

    prefetch(0);

    for (int ib = 0; ib < NPAIR; ib += 6) {
#pragma unroll
        for (int j = 0; j < 6; ++j) {
            const int i = ib + j;
            if (i < NPAIR) {
                // stage prefetched row pair into LDS slot j%3 (ib%3==0 always)
                sbuf[j % 3][tid] = v4f{pa1, pb1, pa2, pb2};
                if (tid < 16) sbuf[j % 3][256 + tid] = v4f{qa1, qb1, qa2, qb2};

                if (i + 1 < NPAIR) prefetch(i + 1);

                __syncthreads();   // RAW on slot j%3; triple buffer kills WAR

                // horizontal 11-tap conv for this thread's column, both rows
                v2f a1 = {0,0}, a2 = {0,0}, a11 = {0,0}, a22 = {0,0}, a12 = {0,0};
                const v4f* sp = &sbuf[j % 3][tid + 3];
#pragma unroll
                for (int k = 0; k < 11; ++k) {
                    const v4f s  = sp[k];
                    const v2f x1 = __builtin_shufflevector(s, s, 0, 1);
                    const v2f x2 = __builtin_shufflevector(s, s, 2, 3);
                    const float g = GW[k];
                    const v2f t1 = g * x1;
                    const v2f t2 = g * x2;
                    a1 += t1;
                    a2 += t2;
                    a11 = __builtin_elementwise_fma(t1, x1, a11);
                    a22 = __builtin_elementwise_fma(t2, x2, a22);
                    a12 = __builtin_elementwise_fma(t1, x2, a12);
                }
                rg1[j] = a1;  rg2[j] = a2;
                rg11[j] = a11; rg22[j] = a22; rg12[j] = a12;
            }

            if (i >= 5 && i < NPAIR) {
                // vertical conv for output rows (y0+2q, y0+2q+1), q = i-5.
                // ring entry m (input pair q+m) sits at slot (j+1+m)%6.
                // out.x taps: {g[2m], g[2m+1]} ; out.y taps: {g[2m-1], g[2m]}
                v2f sx1={0,0}, sy1={0,0}, sx2={0,0}, sy2={0,0};
                v2f sx11={0,0}, sy11={0,0}, sx22={0,0}, sy22={0,0};
                v2f sx12={0,0}, sy12={0,0};
#pragma unroll
                for (int m = 0; m < 6; ++m) {
                    const int s = (j + 1 + m) % 6;
                    const v2f wx = { GWp[2*m + 1], GWp[2*m + 2] };
                    const v2f wy = { GWp[2*m],     GWp[2*m + 1] };
                    sx1  = __builtin_elementwise_fma(wx, rg1[s],  sx1);
                    sy1  = __builtin_elementwise_fma(wy, rg1[s],  sy1);
                    sx2  = __builtin_elementwise_fma(wx, rg2[s],  sx2);
                    sy2  = __builtin_elementwise_fma(wy, rg2[s],  sy2);
                    sx11 = __builtin_elementwise_fma(wx, rg11[s], sx11);
                    sy11 = __builtin_elementwise_fma(wy, rg11[s], sy11);
                    sx22 = __builtin_elementwise_fma(wx, rg22[s], sx22);
                    sy22 = __builtin_elementwise_fma(wy, rg22[s], sy22);
                    sx12 = __builtin_elementwise_fma(wx, rg12[s], sx12);
                    sy12 = __builtin_elementwise_fma(wy, rg12[s], sy12);
                }
                // lane-sum each pk-dot -> {row r, row r+1} packed values
                const v2f m1  = { sx1.x + sx1.y,  sy1.x + sy1.y };
                const v2f m2  = { sx2.x + sx2.y,  sy2.x + sy2.y };
                const v2f e11 = { sx11.x + sx11.y, sy11.x + sy11.y };
                const v2f e22 = { sx22.x + sx22.y, sy22.x + sy22.y };
                const v2f e12 = { sx12.x + sx12.y, sy12.x + sy12.y };

                const v2f mu11 = m1 * m1;
                const v2f mu22 = m2 * m2;
                const v2f mu12 = m1 * m2;
                const v2f zero = {0.0f, 0.0f};
                const v2f one  = {1.0f, 1.0f};
                const v2f sg1  = __builtin_elementwise_max(e11 - mu11, zero);
                const v2f sg2  = __builtin_elementwise_max(e22 - mu22, zero);
                const v2f sg12 = e12 - mu12;
                const v2f num = (2.0f * mu12 + 1e-4f) * (2.0f * sg12 + 9e-4f);
                const v2f den = (mu11 + mu22 + 1e-4f) * (sg1 + sg2 + 9e-4f);
                v2f v = { num.x * __builtin_amdgcn_rcpf(den.x),
                          num.y * __builtin_amdgcn_rcpf(den.y) };
                v = __builtin_elementwise_min(__builtin_elementwise_max(v, zero), one);
                accv += v;
            }
        }
    }

    float acc = accv.x + accv.y;
#pragma unroll
    for (int off = 32; off > 0; off >>= 1)
        acc += __shfl_down(acc, off, 64);
    if ((tid & 63) == 0) wsum[tid >> 6] = acc;
    __syncthreads();
    if (tid == 0) {
        double blocksum = 0.0;
#pragma unroll
        for (int w = 0; w < TPB / 64; ++w) blocksum += (double)wsum[w];
        atomicAdd(partial, blocksum);
    }
}

__global__ void ssim_finalize_kernel(const double* __restrict__ partial,
                                     float* __restrict__ out)
{
    out[0] = 1.0f - (float)(partial[0] / N_PIX);
}

extern "C" void kernel_launch(void* const* d_in, const int* in_sizes, int n_in,
                              void* d_out, int out_size, void* d_ws, size_t ws_size,
                              hipStream_t stream) {
    const float* img1 = (const float*)d_in[0];
    const float* img2 = (const float*)d_in[1];
    float* out = (float*)d_out;
    double* acc = (double*)d_ws;

    hipMemsetAsync(acc, 0, sizeof(double), stream);  // ws re-poisoned each launch

    dim3 grid(IMG / TPB, IMG / SH, PLANES);          // 2 x 8 x 96 = 1536 blocks
    ssim_map_kernel<<<grid, TPB, 0, stream>>>(img1, img2, acc);
    ssim_finalize_kernel<<<1, 1, 0, stream>>>(acc, out);
}

// Round 5
// 249.949 us; speedup vs baseline: 1.6871x; 1.0274x over previous
//
#include <hip/hip_runtime.h>

// SSIM loss v6 — row-pair packed-FP32 formulation:
//   - 1 column per thread, input rows streamed in PAIRS -> every hot op is a
//     v_pk_*_f32 on a {rowA,rowB} v2f with naturally register-aligned operands
//   - LDS entry = float4 {img1[rA], img1[rB], img2[rA], img2[rB]} per column:
//     horizontal 11-tap conv = 11 aligned ds_read_b128, halves are v2f operands
//   - vertical conv: 6-entry row-pair ring, per ring entry a pk-dot with
//     constant weight pairs {g[2m],g[2m+1]} / {g[2m-1],g[2m]}, lane-sum at end.
//   - triple-buffered LDS, one barrier per row-PAIR (37/block)
//   - v6 STRUCTURAL FIX: prefetch(i+1) moved AFTER __syncthreads(). hipcc
//     emits s_waitcnt vmcnt(0) before every s_barrier, so the old order
//     {stage(i); prefetch(i+1); BARRIER} drained the just-issued global loads
//     immediately — full HBM/L3 latency exposed in EVERY barrier interval.
//     That convoy is why VALUBusy sat at ~65% across 27/33.6/67% occupancy
//     (v3/v5/v4-spill experiments). New order {stage(i); BARRIER;
//     prefetch(i+1); compute(i)} flies the loads under ~350cyc of conv;
//     they're consumed at stage(i+1) so vmcnt=0 at the next barrier anyway.
//   - launch bounds restored to the best-known (256,3): v4's (256,6) spilled
//     (VGPR 64->40, WRITE_SIZE 48KB->200MB, 285us); v5's unbounded used 76
//     VGPR -> 16-wave/CU class, occupancy 27%, 123us. Occupancy is NOT the
//     lever; keep the proven 64-VGPR no-spill config and fix the stall.
//     Spill tripwire: WRITE_SIZE must stay ~KB-scale.
// B=32, C=3, H=W=512 fp32; zero padding (pad=5) matches lax conv semantics.

typedef float v2f __attribute__((ext_vector_type(2)));
typedef float v4f __attribute__((ext_vector_type(4)));

constexpr int IMG    = 512;
constexpr int TPB    = 256;          // threads/block; 1 col/thread
constexpr int SH     = 64;           // output rows per block
constexpr int NPAIR  = 37;           // input row-pairs streamed (74 rows)
constexpr int LW     = 272;          // LDS float4 entries per buffer (8 pad each side)
constexpr int PLANES = 32 * 3;      // 96
constexpr double N_PIX = 25165824.0; // 32*3*512*512

__global__ __launch_bounds__(TPB, 3) void ssim_map_kernel(
    const float* __restrict__ img1, const float* __restrict__ img2,
    double* __restrict__ partial)
{
    constexpr float GW[11] = {
        0.0010283801f, 0.0075987583f, 0.0360007721f, 0.1093607008f,
        0.2130055439f, 0.2660117257f, 0.2130055439f, 0.1093607008f,
        0.0360007721f, 0.0075987583f, 0.0010283801f };
    // GWp[k+1] = GW[k], zero-extended both sides (for edge taps of row pairs)
    constexpr float GWp[13] = {
        0.0f,
        0.0010283801f, 0.0075987583f, 0.0360007721f, 0.1093607008f,
        0.2130055439f, 0.2660117257f, 0.2130055439f, 0.1093607008f,
        0.0360007721f, 0.0075987583f, 0.0010283801f,
        0.0f };

    __shared__ v4f  sbuf[3][LW];
    __shared__ float wsum[TPB / 64];

    const int tid   = threadIdx.x;
    const int x0    = blockIdx.x * TPB;     // 0 or 256
    const int y0    = blockIdx.y * SH;
    const int plane = blockIdx.z;

    const float* p1 = img1 + (size_t)plane * IMG * IMG;
    const float* p2 = img2 + (size_t)plane * IMG * IMG;

    // staging columns: main entry L=tid -> col x0+tid-8 ; halo entry L=256+tid
    // (tid<16) -> col x0+248+tid. Out-of-range columns/rows stage 0.0f.
    const int  c   = x0 + tid - 8;
    const bool cok = (unsigned)c < (unsigned)IMG;
    const int  c2  = x0 + 248 + tid;
    const bool c2ok = (unsigned)c2 < (unsigned)IMG;   // only used when tid<16

    // 6-entry row-pair rings for the 5 horizontally-convolved quantities
    v2f rg1[6], rg2[6], rg11[6], rg22[6], rg12[6];

    v2f accv = {0.0f, 0.0f};

    // prefetch registers for the next row pair (4 main + 4 halo)
    float pa1, pb1, pa2, pb2, qa1, qb1, qa2, qb2;
    auto prefetch = [&](int i) {
        const int  rA  = y0 - 5 + 2 * i;
        const int  rB  = rA + 1;
        const bool aok = (unsigned)rA < (unsigned)IMG;
        const bool bok = (unsigned)rB < (unsigned)IMG;
        const size_t oA = (size_t)rA * IMG;
        const size_t oB = (size_t)rB * IMG;
        pa1 = (aok && cok) ? p1[oA + c] : 0.0f;
        pb1 = (bok && cok) ? p1[oB + c] : 0.0f;
        pa2 = (aok && cok) ? p2[oA + c] : 0.0f;
        pb2 = (bok && cok) ? p2[oB + c] : 0.0f;
        if (tid < 16) {
            qa1 = (aok && c2ok) ? p1[oA + c2] : 0.0f;
            qb1 = (bok && c2ok) ? p1[oB + c2] : 0.0f;
            qa2 = (aok && c2ok) ? p2[oA + c2] : 0.0f;
            qb2 = (bok && c2ok) ? p2[oB + c2] : 0.0f;
        }
    };

    prefetch(0);

    for (int ib = 0; ib < NPAIR; ib += 6) {
#pragma unroll
        for (int j = 0; j < 6; ++j) {
            const int i = ib + j;
            if (i < NPAIR) {
                // stage prefetched row pair into LDS slot j%3 (ib%3==0 always).
                // Consuming pf regs here waits vmcnt for loads issued LAST
                // iteration — latency already covered by compute(i-1).
                sbuf[j % 3][tid] = v4f{pa1, pb1, pa2, pb2};
                if (tid < 16) sbuf[j % 3][256 + tid] = v4f{qa1, qb1, qa2, qb2};

                __syncthreads();   // RAW on slot j%3; drains only the ds_write
                                   // (vmcnt already 0 — pf consumed above)

                // issue NEXT pair's global loads now: they fly under the
                // horizontal+vertical conv below (T14 issue-early/write-late)
                if (i + 1 < NPAIR) prefetch(i + 1);

                // horizontal 11-tap conv for this thread's column, both rows
                v2f a1 = {0,0}, a2 = {0,0}, a11 = {0,0}, a22 = {0,0}, a12 = {0,0};
                const v4f* sp = &sbuf[j % 3][tid + 3];
#pragma unroll
                for (int k = 0; k < 11; ++k) {
                    const v4f s  = sp[k];
                    const v2f x1 = __builtin_shufflevector(s, s, 0, 1);
                    const v2f x2 = __builtin_shufflevector(s, s, 2, 3);
                    const float g = GW[k];
                    const v2f t1 = g * x1;
                    const v2f t2 = g * x2;
                    a1 += t1;
                    a2 += t2;
                    a11 = __builtin_elementwise_fma(t1, x1, a11);
                    a22 = __builtin_elementwise_fma(t2, x2, a22);
                    a12 = __builtin_elementwise_fma(t1, x2, a12);
                }
                rg1[j] = a1;  rg2[j] = a2;
                rg11[j] = a11; rg22[j] = a22; rg12[j] = a12;
            }

            if (i >= 5 && i < NPAIR) {
                // vertical conv for output rows (y0+2q, y0+2q+1), q = i-5.
                // ring entry m (input pair q+m) sits at slot (j+1+m)%6.
                // out.x taps: {g[2m], g[2m+1]} ; out.y taps: {g[2m-1], g[2m]}
                v2f sx1={0,0}, sy1={0,0}, sx2={0,0}, sy2={0,0};
                v2f sx11={0,0}, sy11={0,0}, sx22={0,0}, sy22={0,0};
                v2f sx12={0,0}, sy12={0,0};
#pragma unroll
                for (int m = 0; m < 6; ++m) {
                    const int s = (j + 1 + m) % 6;
                    const v2f wx = { GWp[2*m + 1], GWp[2*m + 2] };
                    const v2f wy = { GWp[2*m],     GWp[2*m + 1] };
                    sx1  = __builtin_elementwise_fma(wx, rg1[s],  sx1);
                    sy1  = __builtin_elementwise_fma(wy, rg1[s],  sy1);
                    sx2  = __builtin_elementwise_fma(wx, rg2[s],  sx2);
                    sy2  = __builtin_elementwise_fma(wy, rg2[s],  sy2);
                    sx11 = __builtin_elementwise_fma(wx, rg11[s], sx11);
                    sy11 = __builtin_elementwise_fma(wy, rg11[s], sy11);
                    sx22 = __builtin_elementwise_fma(wx, rg22[s], sx22);
                    sy22 = __builtin_elementwise_fma(wy, rg22[s], sy22);
                    sx12 = __builtin_elementwise_fma(wx, rg12[s], sx12);
                    sy12 = __builtin_elementwise_fma(wy, rg12[s], sy12);
                }
                // lane-sum each pk-dot -> {row r, row r+1} packed values
                const v2f m1  = { sx1.x + sx1.y,  sy1.x + sy1.y };
                const v2f m2  = { sx2.x + sx2.y,  sy2.x + sy2.y };
                const v2f e11 = { sx11.x + sx11.y, sy11.x + sy11.y };
                const v2f e22 = { sx22.x + sx22.y, sy22.x + sy22.y };
                const v2f e12 = { sx12.x + sx12.y, sy12.x + sy12.y };

                const v2f mu11 = m1 * m1;
                const v2f mu22 = m2 * m2;
                const v2f mu12 = m1 * m2;
                const v2f zero = {0.0f, 0.0f};
                const v2f one  = {1.0f, 1.0f};
                const v2f sg1  = __builtin_elementwise_max(e11 - mu11, zero);
                const v2f sg2  = __builtin_elementwise_max(e22 - mu22, zero);
                const v2f sg12 = e12 - mu12;
                const v2f num = (2.0f * mu12 + 1e-4f) * (2.0f * sg12 + 9e-4f);
                const v2f den = (mu11 + mu22 + 1e-4f) * (sg1 + sg2 + 9e-4f);
                v2f v = { num.x * __builtin_amdgcn_rcpf(den.x),
                          num.y * __builtin_amdgcn_rcpf(den.y) };
                v = __builtin_elementwise_min(__builtin_elementwise_max(v, zero), one);
                accv += v;
            }
        }
    }

    float acc = accv.x + accv.y;
#pragma unroll
    for (int off = 32; off > 0; off >>= 1)
        acc += __shfl_down(acc, off, 64);
    if ((tid & 63) == 0) wsum[tid >> 6] = acc;
    __syncthreads();
    if (tid == 0) {
        double blocksum = 0.0;
#pragma unroll
        for (int w = 0; w < TPB / 64; ++w) blocksum += (double)wsum[w];
        atomicAdd(partial, blocksum);
    }
}

__global__ void ssim_finalize_kernel(const double* __restrict__ partial,
                                     float* __restrict__ out)
{
    out[0] = 1.0f - (float)(partial[0] / N_PIX);
}

extern "C" void kernel_launch(void* const* d_in, const int* in_sizes, int n_in,
                              void* d_out, int out_size, void* d_ws, size_t ws_size,
                              hipStream_t stream) {
    const float* img1 = (const float*)d_in[0];
    const float* img2 = (const float*)d_in[1];
    float* out = (float*)d_out;
    double* acc = (double*)d_ws;

    hipMemsetAsync(acc, 0, sizeof(double), stream);  // ws re-poisoned each launch

    dim3 grid(IMG / TPB, IMG / SH, PLANES);          // 2 x 8 x 96 = 1536 blocks
    ssim_map_kernel<<<grid, TPB, 0, stream>>>(img1, img2, acc);
    ssim_finalize_kernel<<<1, 1, 0, stream>>>(acc, out);
}

// Round 6
// 249.657 us; speedup vs baseline: 1.6890x; 1.0012x over previous
//
#include <hip/hip_runtime.h>

// SSIM loss v7 — row-pair packed-FP32 formulation:
//   - 1 column per thread, input rows streamed in PAIRS -> every hot op is a
//     v_pk_*_f32 on a {rowA,rowB} v2f with naturally register-aligned operands
//   - LDS entry = float4 {img1[rA], img1[rB], img2[rA], img2[rB]} per column:
//     horizontal 11-tap conv = 11 aligned ds_read_b128, halves are v2f operands
//   - vertical conv: 6-entry row-pair ring, per ring entry a pk-dot with
//     constant weight pairs {g[2m],g[2m+1]} / {g[2m-1],g[2m]}, lane-sum at end.
//   - triple-buffered LDS, one barrier per row-PAIR; T14 order (v6): prefetch
//     issued AFTER the barrier so global latency hides under conv compute.
//   - v7: SH 64 -> 128 (output rows per block). Two effects:
//       (a) halo amortization: 74 input rows / 64 out -> 138/128, i.e. 15.6%
//           -> 7.8% overhead; ~7% fewer total streamed rows & conv ops.
//       (b) grid (2,4,96) = 768 blocks = EXACTLY 3/CU = the (256,3) residency
//           -> whole grid co-resident, single dispatch wave, no 2nd-round ramp
//           (v6 ran 1536 blocks as 2 sequential waves of 3/CU).
//     Evidence base: VALUBusy pinned ~65-66% across occupancy 27/33/67% and
//     across prefetch placement (v3/v4/v5/v6) -> issue-rate is not the lever;
//     total instruction volume + per-interval latency is. This round cuts
//     volume ~7% with zero structural risk; barrier-batching (3 pairs/barrier,
//     6 slots, 13 barriers) is staged for next round if this lands.
//   - launch bounds (256,3): proven 64-VGPR no-spill config. (256,6) spilled
//     (WRITE_SIZE 48KB->200MB, 285us); unbounded used 76 VGPR, 123us.
//     Spill tripwire: WRITE_SIZE must stay ~KB-scale.
// B=32, C=3, H=W=512 fp32; zero padding (pad=5) matches lax conv semantics.

typedef float v2f __attribute__((ext_vector_type(2)));
typedef float v4f __attribute__((ext_vector_type(4)));

constexpr int IMG    = 512;
constexpr int TPB    = 256;          // threads/block; 1 col/thread
constexpr int SH     = 128;          // output rows per block (v7: 64 -> 128)
constexpr int NPAIR  = (SH + 10) / 2; // 69 input row-pairs streamed (138 rows)
constexpr int LW     = 272;          // LDS float4 entries per buffer (8 pad each side)
constexpr int PLANES = 32 * 3;      // 96
constexpr double N_PIX = 25165824.0; // 32*3*512*512

__global__ __launch_bounds__(TPB, 3) void ssim_map_kernel(
    const float* __restrict__ img1, const float* __restrict__ img2,
    double* __restrict__ partial)
{
    constexpr float GW[11] = {
        0.0010283801f, 0.0075987583f, 0.0360007721f, 0.1093607008f,
        0.2130055439f, 0.2660117257f, 0.2130055439f, 0.1093607008f,
        0.0360007721f, 0.0075987583f, 0.0010283801f };
    // GWp[k+1] = GW[k], zero-extended both sides (for edge taps of row pairs)
    constexpr float GWp[13] = {
        0.0f,
        0.0010283801f, 0.0075987583f, 0.0360007721f, 0.1093607008f,
        0.2130055439f, 0.2660117257f, 0.2130055439f, 0.1093607008f,
        0.0360007721f, 0.0075987583f, 0.0010283801f,
        0.0f };

    __shared__ v4f  sbuf[3][LW];
    __shared__ float wsum[TPB / 64];

    const int tid   = threadIdx.x;
    const int x0    = blockIdx.x * TPB;     // 0 or 256
    const int y0    = blockIdx.y * SH;      // 0,128,256,384
    const int plane = blockIdx.z;

    const float* p1 = img1 + (size_t)plane * IMG * IMG;
    const float* p2 = img2 + (size_t)plane * IMG * IMG;

    // staging columns: main entry L=tid -> col x0+tid-8 ; halo entry L=256+tid
    // (tid<16) -> col x0+248+tid. Out-of-range columns/rows stage 0.0f.
    const int  c   = x0 + tid - 8;
    const bool cok = (unsigned)c < (unsigned)IMG;
    const int  c2  = x0 + 248 + tid;
    const bool c2ok = (unsigned)c2 < (unsigned)IMG;   // only used when tid<16

    // 6-entry row-pair rings for the 5 horizontally-convolved quantities
    v2f rg1[6], rg2[6], rg11[6], rg22[6], rg12[6];

    v2f accv = {0.0f, 0.0f};

    // prefetch registers for the next row pair (4 main + 4 halo)
    float pa1, pb1, pa2, pb2, qa1, qb1, qa2, qb2;
    auto prefetch = [&](int i) {
        const int  rA  = y0 - 5 + 2 * i;
        const int  rB  = rA + 1;
        const bool aok = (unsigned)rA < (unsigned)IMG;
        const bool bok = (unsigned)rB < (unsigned)IMG;
        const size_t oA = (size_t)rA * IMG;
        const size_t oB = (size_t)rB * IMG;
        pa1 = (aok && cok) ? p1[oA + c] : 0.0f;
        pb1 = (bok && cok) ? p1[oB + c] : 0.0f;
        pa2 = (aok && cok) ? p2[oA + c] : 0.0f;
        pb2 = (bok && cok) ? p2[oB + c] : 0.0f;
        if (tid < 16) {
            qa1 = (aok && c2ok) ? p1[oA + c2] : 0.0f;
            qb1 = (bok && c2ok) ? p1[oB + c2] : 0.0f;
            qa2 = (aok && c2ok) ? p2[oA + c2] : 0.0f;
            qb2 = (bok && c2ok) ? p2[oB + c2] : 0.0f;
        }
    };

    prefetch(0);

    for (int ib = 0; ib < NPAIR; ib += 6) {
#pragma unroll
        for (int j = 0; j < 6; ++j) {
            const int i = ib + j;
            if (i < NPAIR) {
                // stage prefetched row pair into LDS slot j%3 (ib%3==0 always).
                // Consuming pf regs here waits vmcnt for loads issued LAST
                // iteration — latency already covered by compute(i-1).
                sbuf[j % 3][tid] = v4f{pa1, pb1, pa2, pb2};
                if (tid < 16) sbuf[j % 3][256 + tid] = v4f{qa1, qb1, qa2, qb2};

                __syncthreads();   // RAW on slot j%3; drains only the ds_write
                                   // (vmcnt already 0 — pf consumed above)

                // issue NEXT pair's global loads now: they fly under the
                // horizontal+vertical conv below (T14 issue-early/write-late)
                if (i + 1 < NPAIR) prefetch(i + 1);

                // horizontal 11-tap conv for this thread's column, both rows
                v2f a1 = {0,0}, a2 = {0,0}, a11 = {0,0}, a22 = {0,0}, a12 = {0,0};
                const v4f* sp = &sbuf[j % 3][tid + 3];
#pragma unroll
                for (int k = 0; k < 11; ++k) {
                    const v4f s  = sp[k];
                    const v2f x1 = __builtin_shufflevector(s, s, 0, 1);
                    const v2f x2 = __builtin_shufflevector(s, s, 2, 3);
                    const float g = GW[k];
                    const v2f t1 = g * x1;
                    const v2f t2 = g * x2;
                    a1 += t1;
                    a2 += t2;
                    a11 = __builtin_elementwise_fma(t1, x1, a11);
                    a22 = __builtin_elementwise_fma(t2, x2, a22);
                    a12 = __builtin_elementwise_fma(t1, x2, a12);
                }
                rg1[j] = a1;  rg2[j] = a2;
                rg11[j] = a11; rg22[j] = a22; rg12[j] = a12;
            }

            if (i >= 5 && i < NPAIR) {
                // vertical conv for output rows (y0+2q, y0+2q+1), q = i-5.
                // ring entry m (input pair q+m) sits at slot (j+1+m)%6.
                // out.x taps: {g[2m], g[2m+1]} ; out.y taps: {g[2m-1], g[2m]}
                v2f sx1={0,0}, sy1={0,0}, sx2={0,0}, sy2={0,0};
                v2f sx11={0,0}, sy11={0,0}, sx22={0,0}, sy22={0,0};
                v2f sx12={0,0}, sy12={0,0};
#pragma unroll
                for (int m = 0; m < 6; ++m) {
                    const int s = (j + 1 + m) % 6;
                    const v2f wx = { GWp[2*m + 1], GWp[2*m + 2] };
                    const v2f wy = { GWp[2*m],     GWp[2*m + 1] };
                    sx1  = __builtin_elementwise_fma(wx, rg1[s],  sx1);
                    sy1  = __builtin_elementwise_fma(wy, rg1[s],  sy1);
                    sx2  = __builtin_elementwise_fma(wx, rg2[s],  sx2);
                    sy2  = __builtin_elementwise_fma(wy, rg2[s],  sy2);
                    sx11 = __builtin_elementwise_fma(wx, rg11[s], sx11);
                    sy11 = __builtin_elementwise_fma(wy, rg11[s], sy11);
                    sx22 = __builtin_elementwise_fma(wx, rg22[s], sx22);
                    sy22 = __builtin_elementwise_fma(wy, rg22[s], sy22);
                    sx12 = __builtin_elementwise_fma(wx, rg12[s], sx12);
                    sy12 = __builtin_elementwise_fma(wy, rg12[s], sy12);
                }
                // lane-sum each pk-dot -> {row r, row r+1} packed values
                const v2f m1  = { sx1.x + sx1.y,  sy1.x + sy1.y };
                const v2f m2  = { sx2.x + sx2.y,  sy2.x + sy2.y };
                const v2f e11 = { sx11.x + sx11.y, sy11.x + sy11.y };
                const v2f e22 = { sx22.x + sx22.y, sy22.x + sy22.y };
                const v2f e12 = { sx12.x + sx12.y, sy12.x + sy12.y };

                const v2f mu11 = m1 * m1;
                const v2f mu22 = m2 * m2;
                const v2f mu12 = m1 * m2;
                const v2f zero = {0.0f, 0.0f};
                const v2f one  = {1.0f, 1.0f};
                const v2f sg1  = __builtin_elementwise_max(e11 - mu11, zero);
                const v2f sg2  = __builtin_elementwise_max(e22 - mu22, zero);
                const v2f sg12 = e12 - mu12;
                const v2f num = (2.0f * mu12 + 1e-4f) * (2.0f * sg12 + 9e-4f);
                const v2f den = (mu11 + mu22 + 1e-4f) * (sg1 + sg2 + 9e-4f);
                v2f v = { num.x * __builtin_amdgcn_rcpf(den.x),
                          num.y * __builtin_amdgcn_rcpf(den.y) };
                v = __builtin_elementwise_min(__builtin_elementwise_max(v, zero), one);
                accv += v;
            }
        }
    }

    float acc = accv.x + accv.y;
#pragma unroll
    for (int off = 32; off > 0; off >>= 1)
        acc += __shfl_down(acc, off, 64);
    if ((tid & 63) == 0) wsum[tid >> 6] = acc;
    __syncthreads();
    if (tid == 0) {
        double blocksum = 0.0;
#pragma unroll
        for (int w = 0; w < TPB / 64; ++w) blocksum += (double)wsum[w];
        atomicAdd(partial, blocksum);
    }
}

__global__ void ssim_finalize_kernel(const double* __restrict__ partial,
                                     float* __restrict__ out)
{
    out[0] = 1.0f - (float)(partial[0] / N_PIX);
}

extern "C" void kernel_launch(void* const* d_in, const int* in_sizes, int n_in,
                              void* d_out, int out_size, void* d_ws, size_t ws_size,
                              hipStream_t stream) {
    const float* img1 = (const float*)d_in[0];
    const float* img2 = (const float*)d_in[1];
    float* out = (float*)d_out;
    double* acc = (double*)d_ws;

    hipMemsetAsync(acc, 0, sizeof(double), stream);  // ws re-poisoned each launch

    dim3 grid(IMG / TPB, IMG / SH, PLANES);          // 2 x 4 x 96 = 768 blocks = 3/CU
    ssim_map_kernel<<<grid, TPB, 0, stream>>>(img1, img2, acc);
    ssim_finalize_kernel<<<1, 1, 0, stream>>>(acc, out);
}